// Round 4
// baseline (19.722 us; speedup 1.0000x reference)
//
#include <hip/hip_runtime.h>

#define NATOMS 1024
#define NBATCH 4
#define TSIZE  1008

typedef float v2f __attribute__((ext_vector_type(2)));

// ---------------------------------------------------------------------------
// R21: amortization + floor probe. R20's two-kernel split failed correctness
// (handoff through d_ws — mechanism not identifiable from here; shelved).
// Back to the proven monolithic structure, with ONE change: 512 blocks x
// 512 thr, 8 atoms/block, Phase B run as TWO sequential passes (rep=0,1)
// over the same LDS partition. Halves dispatch count and Phase-A
// replication (512 partitions, was 1024), makes residency uniform
// (2 blocks/CU exactly, was ragged 768+256), at 4 waves/SIMD (was 6).
// Per-atom ladder math, FP summation order, reduction, and store mapping
// are byte-identical to the 18.65us kernel.
// Decision rule: ~17.x -> dispatch/PhaseA was the term; ~18.6 -> fixed
// floor, declare done; 20+ -> occupancy binds, revert grid.
// ---------------------------------------------------------------------------
__global__ __launch_bounds__(512, 6) void aev_fused_kernel(
    const int* __restrict__ species,
    const float* __restrict__ coords,
    float* __restrict__ out)
{
    __shared__ float2 lxy[NATOMS];
    __shared__ float  lz[NATOMS];
    __shared__ int    cnt[16][4];
    __shared__ int    basearr[16][4];
    __shared__ int    lseg[5];

    const int tid      = threadIdx.x;
    const int b        = blockIdx.x >> 7;          // 128 blocks per batch
    const int atomBase = (blockIdx.x & 127) * 8;   // 8 atoms per block
    const int lane     = tid & 63;
    const int w        = tid >> 6;                 // 0..7

    const unsigned long long lt = (1ull << lane) - 1ull;

    // ---- Phase A1: ballots. Wave w, chunk c covers group g = 8c+w ----
    int sp_[2], rank_[2];
#pragma unroll
    for (int c = 0; c < 2; ++c) {
        const int g  = 8 * c + w;                  // 0..15
        const int a  = 64 * g + lane;
        const int sp = species[b * NATOMS + a];
        sp_[c] = sp;
        int r = 0;
#pragma unroll
        for (int s = 0; s < 4; ++s) {
            const unsigned long long m = __ballot(sp == s);
            if (sp == s) r = __popcll(m & lt);
            if (lane == 0) cnt[g][s] = __popcll(m);
        }
        rank_[c] = r;
    }
    __syncthreads();

    // ---- Phase A2: wave 0 exclusive scan over 64 counts (s-major, g-minor) ----
    if (w == 0) {
        const int s = lane >> 4, g = lane & 15;
        const int v = cnt[g][s];
        int inc = v;
#pragma unroll
        for (int off = 1; off < 64; off <<= 1) {
            const int u = __shfl_up(inc, off, 64);
            if (lane >= off) inc += u;
        }
        const int exc = inc - v;
        basearr[g][s] = exc;
        if (g == 0)     lseg[s] = exc;
        if (lane == 63) lseg[4] = inc;             // == NATOMS
    }
    __syncthreads();

    // ---- Phase A3: scatter coords into species-partitioned LDS ----
#pragma unroll
    for (int c = 0; c < 2; ++c) {
        const int g   = 8 * c + w;
        const int a   = 64 * g + lane;
        const int pos = basearr[g][sp_[c]] + rank_[c];
        const float x = coords[(b * NATOMS + a) * 3 + 0];
        const float y = coords[(b * NATOMS + a) * 3 + 1];
        const float z = coords[(b * NATOMS + a) * 3 + 2];
        lxy[pos] = make_float2(x, y);
        lz[pos]  = z;
    }
    __syncthreads();

    // tail zero-fill (cols 64..1007) of this block's 8 rows — issued here so
    // the stores drain while Phase B computes (disjoint from result cols 0..63).
    {
        const float4 z4 = make_float4(0.f, 0.f, 0.f, 0.f);
        for (int t = tid; t < 8 * 236; t += 512) {
            const int r = t / 236;
            const int c = t - r * 236;
            float4* p = reinterpret_cast<float4*>(
                out + (size_t)(b * NATOMS + atomBase + r) * TSIZE + 64 + c * 4);
            *p = z4;
        }
    }

    // ---- Phase B: two sequential atom-sets over the same partition ----
    const int aid = w >> 1;          // 0..3, atom within set
    const int h   = w & 1;           // species half

#pragma unroll 1
    for (int rep = 0; rep < 2; ++rep) {
        const int i = atomBase + 4 * rep + aid;
        const float cx = coords[(b * NATOMS + i) * 3 + 0];
        const float cy = coords[(b * NATOMS + i) * 3 + 1];
        const float cz = coords[(b * NATOMS + i) * 3 + 2];

        v2f accp[2][8];
#pragma unroll
        for (int sl = 0; sl < 2; ++sl)
#pragma unroll
            for (int m = 0; m < 8; ++m) accp[sl][m] = (v2f){0.f, 0.f};

#pragma unroll
        for (int sl = 0; sl < 2; ++sl) {
            const int s   = 2 * h + sl;
            const int beg = lseg[s];
            const int end = lseg[s + 1];

            // rotated loop with 1-deep prefetch; LDS holds a full permutation
            // of the 1024 atoms, so clamped reads (& 1023) are always safe.
            int jj = beg + lane;
            float2 xy = lxy[jj & (NATOMS - 1)];
            float  zz = lz[jj & (NATOMS - 1)];

            while (jj < end) {
                const int    jn  = jj + 64;
                const float2 xyn = lxy[jn & (NATOMS - 1)];
                const float  zn  = lz[jn & (NATOMS - 1)];

                const float dx = xy.x - cx;
                const float dy = xy.y - cy;
                const float dz = zz   - cz;
                const float d2 = fmaf(dx, dx, fmaf(dy, dy, dz * dz));
                const float d  = __builtin_amdgcn_sqrtf(d2);
                const float dc = fminf(d, 5.2f);
                // fc from clamped dc: exact 0 at/beyond cutoff
                const float fc = fmaf(0.5f, __builtin_amdgcn_cosf(dc * 0.09615384615f), 0.5f);

                const float t7 = fmaf(dc, 4.80448963f, -13.36248679f);
                const float a  = 2.5824132f * t7;
                float ed = __builtin_amdgcn_exp2f(-(t7 * t7));
                const float g  = __builtin_amdgcn_exp2f(a);
                const float gi = __builtin_amdgcn_exp2f(-a);
                ed *= fc;

                v2f e;
                e.x = ed;
                e.y = ed * (g * 0.3148664f);                 // == exp2(-t8^2)*fc
                v2f r = (v2f){gi, g} * (v2f){0.3148664f, 0.0312141f};  // pk_mul

                accp[sl][0] += e;                            // pk_add
#pragma unroll
                for (int m = 1; m <= 7; ++m) {
                    e *= r;                                  // pk_mul
                    r *= 0.0991402f;                         // pk_mul
                    accp[sl][m] += e;                        // pk_add
                }

                jj = jn; xy = xyn; zz = zn;
            }
        }

        // unpack to the proven acc[32] layout (static indices)
        float acc[32];
#pragma unroll
        for (int sl = 0; sl < 2; ++sl) {
            acc[sl * 16 + 7] = accp[sl][0].x;
            acc[sl * 16 + 8] = accp[sl][0].y;
#pragma unroll
            for (int m = 1; m <= 7; ++m) {
                acc[sl * 16 + 7 - m] = accp[sl][m].x;
                acc[sl * 16 + 8 + m] = accp[sl][m].y;
            }
        }

        // Reduction: m=32,16 via permlane-swap, m=8,4,2 + final xor1.
#pragma unroll
        for (int q = 0; q < 16; ++q) {
            asm("v_permlane32_swap_b32 %0, %1" : "+v"(acc[q]), "+v"(acc[q + 16]));
            acc[q] += acc[q + 16];
        }
#pragma unroll
        for (int q = 0; q < 8; ++q) {
            asm("v_permlane16_swap_b32 %0, %1" : "+v"(acc[q]), "+v"(acc[q + 8]));
            acc[q] += acc[q + 8];
        }
#pragma unroll
        for (int step = 0; step < 3; ++step) {
            const int m = 8 >> step;         // 8,4,2
            const int n = 4 >> step;         // live pairs: 4,2,1
            const bool hi = (lane & m) != 0;
#pragma unroll
            for (int q = 0; q < n; ++q) {
                const float keep = hi ? acc[q + n] : acc[q];
                const float send = hi ? acc[q] : acc[q + n];
                acc[q] = keep + __shfl_xor(send, m, 64);
            }
        }
        const float tot = acc[0] + __shfl_xor(acc[0], 1, 64);

        if (!(lane & 1))
            out[(size_t)(b * NATOMS + i) * TSIZE + h * 32 + (lane >> 1)] = tot;
    }
}

extern "C" void kernel_launch(void* const* d_in, const int* in_sizes, int n_in,
                              void* d_out, int out_size, void* d_ws, size_t ws_size,
                              hipStream_t stream)
{
    const int*   species = (const int*)d_in[0];
    const float* coords  = (const float*)d_in[1];
    float* out = (float*)d_out;

    aev_fused_kernel<<<512, 512, 0, stream>>>(species, coords, out);
}

// Round 5
// 18.475 us; speedup vs baseline: 1.0675x; 1.0675x over previous
//
#include <hip/hip_runtime.h>

#define NATOMS 1024
#define NBATCH 4
#define TSIZE  1008

typedef float v2f __attribute__((ext_vector_type(2)));

// ---------------------------------------------------------------------------
// R22: single-variable occupancy probe on the proven 18.65us R0 body.
// Evidence: wave count is the only knob that has ever moved dur_us in the
// predicted direction (R18 reg-starve +10.8; R21 4-waves +1.1; all loop/
// barrier/dispatch changes +-0.2). R0 sits at 85 VGPR = exactly 6 waves/SIMD
// (510/512 pool). This round: identical body, __launch_bounds__(512, 7)
// -> 73-reg cap, shaving 12 regs (gentle, vs R18's fatal 85->64 on a ~60-live
// loop). Loop live-set (~60) fits; pressure peak is the post-loop reduction
// where a small spill is off the critical path.
// Decision rule: 17.2-18.0 -> occupancy was binding, keep; 19.5+ -> spilled,
// revert to 6; 18.4-18.9 -> latency-hiding saturated, declare floor.
// ---------------------------------------------------------------------------
__global__ __launch_bounds__(512, 7) void aev_fused_kernel(
    const int* __restrict__ species,
    const float* __restrict__ coords,
    float* __restrict__ out)
{
    __shared__ float2 lxy[NATOMS];
    __shared__ float  lz[NATOMS];
    __shared__ int    cnt[16][4];
    __shared__ int    basearr[16][4];
    __shared__ int    lseg[5];

    const int tid      = threadIdx.x;
    const int b        = blockIdx.x >> 8;          // 256 blocks per batch
    const int atomBase = (blockIdx.x & 255) * 4;   // 4 atoms per block
    const int lane     = tid & 63;
    const int w        = tid >> 6;                 // 0..7

    const unsigned long long lt = (1ull << lane) - 1ull;

    // ---- Phase A1: ballots. Wave w, chunk c covers group g = 8c+w ----
    int sp_[2], rank_[2];
#pragma unroll
    for (int c = 0; c < 2; ++c) {
        const int g  = 8 * c + w;                  // 0..15
        const int a  = 64 * g + lane;
        const int sp = species[b * NATOMS + a];
        sp_[c] = sp;
        int r = 0;
#pragma unroll
        for (int s = 0; s < 4; ++s) {
            const unsigned long long m = __ballot(sp == s);
            if (sp == s) r = __popcll(m & lt);
            if (lane == 0) cnt[g][s] = __popcll(m);
        }
        rank_[c] = r;
    }
    __syncthreads();

    // ---- Phase A2: wave 0 exclusive scan over 64 counts (s-major, g-minor) ----
    if (w == 0) {
        const int s = lane >> 4, g = lane & 15;
        const int v = cnt[g][s];
        int inc = v;
#pragma unroll
        for (int off = 1; off < 64; off <<= 1) {
            const int u = __shfl_up(inc, off, 64);
            if (lane >= off) inc += u;
        }
        const int exc = inc - v;
        basearr[g][s] = exc;
        if (g == 0)     lseg[s] = exc;
        if (lane == 63) lseg[4] = inc;             // == NATOMS
    }
    __syncthreads();

    // ---- Phase A3: scatter coords into species-partitioned LDS ----
#pragma unroll
    for (int c = 0; c < 2; ++c) {
        const int g   = 8 * c + w;
        const int a   = 64 * g + lane;
        const int pos = basearr[g][sp_[c]] + rank_[c];
        const float x = coords[(b * NATOMS + a) * 3 + 0];
        const float y = coords[(b * NATOMS + a) * 3 + 1];
        const float z = coords[(b * NATOMS + a) * 3 + 2];
        lxy[pos] = make_float2(x, y);
        lz[pos]  = z;
    }

    // tail zero-fill (cols 64..1007) of this block's 4 rows
    {
        const float4 z4 = make_float4(0.f, 0.f, 0.f, 0.f);
        for (int t = tid; t < 4 * 236; t += 512) {
            const int r = t / 236;
            const int c = t - r * 236;
            float4* p = reinterpret_cast<float4*>(
                out + (size_t)(b * NATOMS + atomBase + r) * TSIZE + 64 + c * 4);
            *p = z4;
        }
    }
    __syncthreads();

    // ---- Phase B (byte-identical math to R17) ----
    const int aid = w >> 1;          // 0..3, atom within block
    const int h   = w & 1;           // species half
    const int i   = atomBase + aid;
    const float cx = coords[(b * NATOMS + i) * 3 + 0];
    const float cy = coords[(b * NATOMS + i) * 3 + 1];
    const float cz = coords[(b * NATOMS + i) * 3 + 2];

    v2f accp[2][8];
#pragma unroll
    for (int sl = 0; sl < 2; ++sl)
#pragma unroll
        for (int m = 0; m < 8; ++m) accp[sl][m] = (v2f){0.f, 0.f};

#pragma unroll
    for (int sl = 0; sl < 2; ++sl) {
        const int s   = 2 * h + sl;
        const int beg = lseg[s];
        const int end = lseg[s + 1];
        for (int jj = beg + lane; jj < end; jj += 64) {
            const float2 xy = lxy[jj];
            const float  zz = lz[jj];
            const float dx = xy.x - cx;
            const float dy = xy.y - cy;
            const float dz = zz   - cz;
            const float d2 = fmaf(dx, dx, fmaf(dy, dy, dz * dz));
            const float d  = __builtin_amdgcn_sqrtf(d2);
            const float dc = fminf(d, 5.2f);
            // fc from clamped dc: exact 0 at/beyond cutoff (cos(0.5 rev) = -1)
            const float fc = fmaf(0.5f, __builtin_amdgcn_cosf(dc * 0.09615384615f), 0.5f);

            const float t7 = fmaf(dc, 4.80448963f, -13.36248679f);
            const float a  = 2.5824132f * t7;
            float ed = __builtin_amdgcn_exp2f(-(t7 * t7));
            const float g  = __builtin_amdgcn_exp2f(a);
            const float gi = __builtin_amdgcn_exp2f(-a);
            ed *= fc;

            v2f e;
            e.x = ed;
            e.y = ed * (g * 0.3148664f);                 // == exp2(-t8^2)*fc
            v2f r = (v2f){gi, g} * (v2f){0.3148664f, 0.0312141f};  // pk_mul

            accp[sl][0] += e;                            // pk_add
#pragma unroll
            for (int m = 1; m <= 7; ++m) {
                e *= r;                                  // pk_mul
                r *= 0.0991402f;                         // pk_mul
                accp[sl][m] += e;                        // pk_add
            }
        }
    }

    // unpack to the proven acc[32] layout (static indices)
    float acc[32];
#pragma unroll
    for (int sl = 0; sl < 2; ++sl) {
        acc[sl * 16 + 7] = accp[sl][0].x;
        acc[sl * 16 + 8] = accp[sl][0].y;
#pragma unroll
        for (int m = 1; m <= 7; ++m) {
            acc[sl * 16 + 7 - m] = accp[sl][m].x;
            acc[sl * 16 + 8 + m] = accp[sl][m].y;
        }
    }

    // Reduction: m=32,16 via permlane-swap (R17-corrected direction),
    // m=8,4,2 + final xor1 in cndmask form.
#pragma unroll
    for (int q = 0; q < 16; ++q) {
        asm("v_permlane32_swap_b32 %0, %1" : "+v"(acc[q]), "+v"(acc[q + 16]));
        acc[q] += acc[q + 16];
    }
#pragma unroll
    for (int q = 0; q < 8; ++q) {
        asm("v_permlane16_swap_b32 %0, %1" : "+v"(acc[q]), "+v"(acc[q + 8]));
        acc[q] += acc[q + 8];
    }
#pragma unroll
    for (int step = 0; step < 3; ++step) {
        const int m = 8 >> step;         // 8,4,2
        const int n = 4 >> step;         // live pairs: 4,2,1
        const bool hi = (lane & m) != 0;
#pragma unroll
        for (int q = 0; q < n; ++q) {
            const float keep = hi ? acc[q + n] : acc[q];
            const float send = hi ? acc[q] : acc[q + n];
            acc[q] = keep + __shfl_xor(send, m, 64);
        }
    }
    const float tot = acc[0] + __shfl_xor(acc[0], 1, 64);

    if (!(lane & 1))
        out[(size_t)(b * NATOMS + i) * TSIZE + h * 32 + (lane >> 1)] = tot;
}

extern "C" void kernel_launch(void* const* d_in, const int* in_sizes, int n_in,
                              void* d_out, int out_size, void* d_ws, size_t ws_size,
                              hipStream_t stream)
{
    const int*   species = (const int*)d_in[0];
    const float* coords  = (const float*)d_in[1];
    float* out = (float*)d_out;

    aev_fused_kernel<<<1024, 512, 0, stream>>>(species, coords, out);
}